// Round 12
// baseline (603.227 us; speedup 1.0000x reference)
//
#include <hip/hip_runtime.h>
#include <hip/hip_bf16.h>

// CADTopoEncoder: hetero-GNN (point/edge/face), 2 SAGE layers + LN + pool.
// bf16 hidden state (in place); mfma_f32_16x16x32_bf16 for all 64x64 matmuls
// (one 11-job dispatch/layer); merged gf dispatch (3 dst types) with a 3-WAY
// MERGED gather loop (3 independent load chains in flight per dst group).
// CSR build: two-level counting sort; bed aliases g_all.

#define POOL_SPLIT 4
#define NBUCK 49
#define ABLK 4096

typedef __attribute__((ext_vector_type(8))) short bf8_t;   // 8 bf16 in 4 VGPRs
typedef __attribute__((ext_vector_type(4))) float f32x4;

__device__ __forceinline__ ushort f2bf(float f) {
  union { __hip_bfloat16 b; ushort u; } v;
  v.b = __float2bfloat16(f);
  return v.u;
}
__device__ __forceinline__ float u2f(ushort u) {
  union { ushort u; __hip_bfloat16 b; } v;
  v.u = u;
  return __bfloat162float(v.b);
}

// ---------------- prep: weights -> bf16 MFMA fragment order, summed biases ----
__global__ __launch_bounds__(256) void prep_kernel(
    const float* __restrict__ Wl, const float* __restrict__ Wr,
    const float* __restrict__ bl, const float* __restrict__ w2p,
    const float* __restrict__ w2e, const float* __restrict__ w2f,
    ushort* __restrict__ fw, float* __restrict__ bls) {
  int idx = blockIdx.x * blockDim.x + threadIdx.x;
  if (idx < 25 * 4096) {
    int m = idx >> 12, e = idx & 4095;
    int i8 = e >> 3, b = e & 7;
    int lane = i8 & 63, cb = i8 >> 6;
    int ks = cb & 1, ct = cb >> 1;
    int k = ks * 32 + ((lane >> 4) << 3) + b;
    int col = (ct << 4) + (lane & 15);
    int widx = (k << 6) + col;
    float v;
    if (m < 16) {
      v = Wl[(size_t)m * 4096 + widx];
    } else if (m < 22) {
      int c = m - 16, i = c / 3, t = c % 3;
      int rb = (t == 0) ? 0 : ((t == 1) ? 6 : 3);
      int rc = (t == 1) ? 2 : 3;
      v = 0.f;
      for (int r = 0; r < rc; ++r) v += Wr[(size_t)(i * 8 + rb + r) * 4096 + widx];
    } else {
      const float* w2 = (m == 22) ? w2p : ((m == 23) ? w2e : w2f);
      v = w2[widx];
    }
    fw[idx] = f2bf(v);
  } else if (idx < 25 * 4096 + 6 * 64) {
    int j = idx - 25 * 4096;
    int c = j >> 6, e = j & 63;
    int i = c / 3, t = c % 3;
    int rb = (t == 0) ? 0 : ((t == 1) ? 6 : 3);
    int rc = (t == 1) ? 2 : 3;
    float s = 0.f;
    for (int r = 0; r < rc; ++r) s += bl[(i * 8 + rb + r) * 64 + e];
    bls[c * 64 + e] = s;
  }
}

// ---------------- batched MFMA GEMM: up to 12 jobs per dispatch --------------
struct GJob { const ushort* A; const ushort* W; const float* bias; ushort* C; int n; };
struct GJobs12 { GJob j[12]; };

__device__ __forceinline__ GJob gsel(const GJobs12& js, int y) {
  switch (y) {
    case 0: return js.j[0];  case 1: return js.j[1];  case 2: return js.j[2];
    case 3: return js.j[3];  case 4: return js.j[4];  case 5: return js.j[5];
    case 6: return js.j[6];  case 7: return js.j[7];  case 8: return js.j[8];
    case 9: return js.j[9];  case 10: return js.j[10]; default: return js.j[11];
  }
}

__global__ __launch_bounds__(256) void gemm_multi_kernel(GJobs12 js) {
  GJob jb = gsel(js, blockIdx.y);
  const int n = jb.n;
  const int lane = threadIdx.x & 63;
  const int wid = (blockIdx.x * blockDim.x + threadIdx.x) >> 6;
  const int r0 = wid * 32;
  if (r0 >= n) return;
  bf8_t bw[8];
#pragma unroll
  for (int i = 0; i < 8; ++i)
    bw[i] = *(const bf8_t*)(jb.W + ((i << 6) + lane) * 8);
  const int koff = ((lane >> 4) << 3);
  int ra = r0 + (lane & 15);
  int rb = ra + 16;
  ra = min(ra, n - 1);
  rb = min(rb, n - 1);
  const bf8_t a00 = *(const bf8_t*)(jb.A + (size_t)ra * 64 + koff);
  const bf8_t a01 = *(const bf8_t*)(jb.A + (size_t)ra * 64 + 32 + koff);
  const bf8_t a10 = *(const bf8_t*)(jb.A + (size_t)rb * 64 + koff);
  const bf8_t a11 = *(const bf8_t*)(jb.A + (size_t)rb * 64 + 32 + koff);
  f32x4 acc[8];
#pragma unroll
  for (int i = 0; i < 8; ++i) acc[i] = (f32x4){0.f, 0.f, 0.f, 0.f};
#pragma unroll
  for (int ct = 0; ct < 4; ++ct) {
    acc[ct]     = __builtin_amdgcn_mfma_f32_16x16x32_bf16(a00, bw[ct * 2 + 0], acc[ct], 0, 0, 0);
    acc[ct]     = __builtin_amdgcn_mfma_f32_16x16x32_bf16(a01, bw[ct * 2 + 1], acc[ct], 0, 0, 0);
    acc[4 + ct] = __builtin_amdgcn_mfma_f32_16x16x32_bf16(a10, bw[ct * 2 + 0], acc[4 + ct], 0, 0, 0);
    acc[4 + ct] = __builtin_amdgcn_mfma_f32_16x16x32_bf16(a11, bw[ct * 2 + 1], acc[4 + ct], 0, 0, 0);
  }
  float bv[4] = {0.f, 0.f, 0.f, 0.f};
  if (jb.bias) {
#pragma unroll
    for (int ct = 0; ct < 4; ++ct) bv[ct] = jb.bias[ct * 16 + (lane & 15)];
  }
  const int rowb = r0 + ((lane >> 4) << 2);
  const int cb = lane & 15;
#pragma unroll
  for (int rt = 0; rt < 2; ++rt) {
#pragma unroll
    for (int q = 0; q < 4; ++q) {
      int row = rowb + rt * 16 + q;
      if (row < n) {
#pragma unroll
        for (int ct = 0; ct < 4; ++ct)
          jb.C[(size_t)row * 64 + ct * 16 + cb] = f2bf(acc[rt * 4 + ct][q] + bv[ct]);
      }
    }
  }
}

// ---------------- mlp stage 1 (3 types in one dispatch) ----------------------
template <int FIN>
__device__ __forceinline__ void mlp1_body(
    const float* __restrict__ x, const float* __restrict__ w1,
    const float* __restrict__ b1, ushort* __restrict__ h1, int n) {
  const int lane = threadIdx.x & 63;
  int wid = (blockIdx.x * blockDim.x + threadIdx.x) >> 6;
  const int nw = (gridDim.x * blockDim.x) >> 6;
  float w1c[FIN];
#pragma unroll
  for (int k = 0; k < FIN; ++k) w1c[k] = w1[k * 64 + lane];
  const float b1v = b1[lane];
  for (int r = wid; r < n; r += nw) {
    float s = b1v;
#pragma unroll
    for (int k = 0; k < FIN; ++k) s = fmaf(x[(size_t)r * FIN + k], w1c[k], s);
    h1[(size_t)r * 64 + lane] = f2bf(fmaxf(s, 0.f));
  }
}

struct MLPJob { const float* x; const float* w1; const float* b1; ushort* o; int n; };
struct MLPack { MLPJob j[3]; };

__global__ __launch_bounds__(256) void mlp1_kernel(MLPack a) {
  if (blockIdx.y == 0)      mlp1_body<3>(a.j[0].x, a.j[0].w1, a.j[0].b1, a.j[0].o, a.j[0].n);
  else if (blockIdx.y == 1) mlp1_body<2>(a.j[1].x, a.j[1].w1, a.j[1].b1, a.j[1].o, a.j[1].n);
  else                      mlp1_body<16>(a.j[2].x, a.j[2].w1, a.j[2].b1, a.j[2].o, a.j[2].n);
}

// ---------------- CSR build: two-level counting sort -------------------------
struct EIPack {
  const int* e0; const int* e1; const int* e2; const int* e3;
  const int* e4; const int* e5; const int* e6; const int* e7;
  int b0, b1, b2, b3, b4, b5, b6, b7;
};

__device__ __forceinline__ void ei_sel(const EIPack& t, int r, const int*& ei, int& b) {
  switch (r) {
    case 0: ei = t.e0; b = t.b0; break;
    case 1: ei = t.e1; b = t.b1; break;
    case 2: ei = t.e2; b = t.b2; break;
    case 3: ei = t.e3; b = t.b3; break;
    case 4: ei = t.e4; b = t.b4; break;
    case 5: ei = t.e5; b = t.b5; break;
    case 6: ei = t.e6; b = t.b6; break;
    default: ei = t.e7; b = t.b7; break;
  }
}

__device__ __forceinline__ int rel_shift(int rel) {
  return rel < 3 ? 12 : (rel < 6 ? 10 : 11);  // P:4096, F:1024, E:2048 dsts/bucket
}

__global__ __launch_bounds__(256) void binA1_kernel(EIPack t, int* __restrict__ counts,
                                                    int E, int nblk) {
  __shared__ int hist[NBUCK];
  int rel = blockIdx.x % 8, blk = blockIdx.x / 8;
  const int* ei; int bb;
  ei_sel(t, rel, ei, bb);
  int shift = rel_shift(rel);
  for (int i = threadIdx.x; i < NBUCK; i += 256) hist[i] = 0;
  __syncthreads();
  int e0 = blk * ABLK;
  for (int i = threadIdx.x; i < ABLK; i += 256) {
    int e = e0 + i;
    if (e < E) {
      int d = __builtin_nontemporal_load(ei + E + e);
      atomicAdd(&hist[d >> shift], 1);
    }
  }
  __syncthreads();
  for (int i = threadIdx.x; i < NBUCK; i += 256)
    counts[(rel * NBUCK + i) * nblk + blk] = hist[i];
}

__global__ __launch_bounds__(256) void binA2_kernel(EIPack t, const int* __restrict__ coff,
                                                    int2* __restrict__ bed,
                                                    int E, int nblk) {
  __shared__ int cur[NBUCK];
  int rel = blockIdx.x % 8, blk = blockIdx.x / 8;
  const int* ei; int bb;
  ei_sel(t, rel, ei, bb);
  int shift = rel_shift(rel);
  for (int i = threadIdx.x; i < NBUCK; i += 256)
    cur[i] = coff[(rel * NBUCK + i) * nblk + blk];
  __syncthreads();
  int e0 = blk * ABLK;
  for (int i = threadIdx.x; i < ABLK; i += 256) {
    int e = e0 + i;
    if (e < E) {
      int s = __builtin_nontemporal_load(ei + e);
      int d = __builtin_nontemporal_load(ei + E + e);
      int p = atomicAdd(&cur[d >> shift], 1);
      bed[p] = make_int2(s, d);
    }
  }
}

__global__ __launch_bounds__(256) void binB_kernel(const int* __restrict__ coff,
                                                   const int2* __restrict__ bed,
                                                   int* __restrict__ off,
                                                   int* __restrict__ srcs,
                                                   int nblk, int NP_, int NF_, int NE_,
                                                   int Etot) {
  __shared__ int hist[4096];
  __shared__ int wsum[4];
  int gb = blockIdx.x;                    // 0..8*NBUCK-1
  int rel = gb / NBUCK, b = gb % NBUCK;
  int shift = rel_shift(rel);
  int D = 1 << shift;
  int ndst_r = rel < 3 ? NP_ : (rel < 6 ? NF_ : NE_);
  int rbase = rel < 3 ? rel * NP_
            : (rel < 6 ? 3 * NP_ + (rel - 3) * NF_
                       : 3 * NP_ + 3 * NF_ + (rel - 6) * NE_);
  int d0 = b << shift;
  int Dl = min(D, ndst_r - d0);
  int ebase = coff[gb * nblk];
  int eend  = coff[(gb + 1) * nblk];
  for (int i = threadIdx.x; i < D; i += 256) hist[i] = 0;
  __syncthreads();
  for (int e = ebase + threadIdx.x; e < eend; e += 256)
    atomicAdd(&hist[bed[e].y - d0], 1);
  __syncthreads();
  const int PT = D >> 8;
  int tbase = threadIdx.x * PT;
  int ts = 0;
  for (int k = 0; k < PT; ++k) ts += hist[tbase + k];
  int lane = threadIdx.x & 63, w = threadIdx.x >> 6;
  int x = ts;
#pragma unroll
  for (int dd = 1; dd < 64; dd <<= 1) {
    int y = __shfl_up(x, dd, 64);
    if (lane >= dd) x += y;
  }
  if (lane == 63) wsum[w] = x;
  __syncthreads();
  int woff = 0;
#pragma unroll
  for (int k = 0; k < 4; ++k)
    if (k < w) woff += wsum[k];
  int pos = woff + x - ts;
  for (int k = 0; k < PT; ++k) {
    int c = hist[tbase + k];
    hist[tbase + k] = pos;
    if (tbase + k < Dl) off[rbase + d0 + tbase + k] = ebase + pos;
    pos += c;
  }
  __syncthreads();
  for (int e = ebase + threadIdx.x; e < eend; e += 256) {
    int2 sd = bed[e];
    int p = atomicAdd(&hist[sd.y - d0], 1);
    srcs[ebase + p] = sd.x;
  }
  if (gb == 0 && threadIdx.x == 0)
    off[3 * NP_ + 3 * NF_ + 2 * NE_] = Etot;
}

__global__ __launch_bounds__(256) void scan1_kernel(const int* __restrict__ cnt,
                                                    int* __restrict__ part, int n) {
  __shared__ int wt[4];
  int base = blockIdx.x * 1024;
  int t = 0;
  for (int i = threadIdx.x; i < 1024; i += 256) {
    int idx = base + i;
    if (idx < n) t += cnt[idx];
  }
#pragma unroll
  for (int d = 32; d > 0; d >>= 1) t += __shfl_xor(t, d, 64);
  if ((threadIdx.x & 63) == 0) wt[threadIdx.x >> 6] = t;
  __syncthreads();
  if (threadIdx.x == 0) part[blockIdx.x] = wt[0] + wt[1] + wt[2] + wt[3];
}

__global__ __launch_bounds__(1024) void scan2_kernel(int* __restrict__ part,
                                                     int* __restrict__ off, int nb,
                                                     int n, int total) {
  __shared__ int lds[1024];
  int tid = threadIdx.x;
  int v = (tid < nb) ? part[tid] : 0;
  lds[tid] = v;
  __syncthreads();
  for (int d = 1; d < 1024; d <<= 1) {
    int y = (tid >= d) ? lds[tid - d] : 0;
    __syncthreads();
    lds[tid] += y;
    __syncthreads();
  }
  if (tid < nb) part[tid] = lds[tid] - v;  // exclusive
  if (tid == 0) off[n] = total;
}

__global__ __launch_bounds__(256) void scan3_kernel(const int* cnt,
                                                    const int* __restrict__ part,
                                                    int* __restrict__ out, int n) {
  __shared__ int wt[4];
  int base = blockIdx.x * 1024 + threadIdx.x * 4;
  int c[4];
#pragma unroll
  for (int k = 0; k < 4; ++k) {
    int idx = base + k;
    c[k] = (idx < n) ? cnt[idx] : 0;
  }
  int t = c[0] + c[1] + c[2] + c[3];
  int lane = threadIdx.x & 63, w = threadIdx.x >> 6;
  int x = t;
#pragma unroll
  for (int d = 1; d < 64; d <<= 1) {
    int y = __shfl_up(x, d, 64);
    if (lane >= d) x += y;
  }
  int ex = x - t;
  if (lane == 63) wt[w] = x;
  __syncthreads();
  int woff = 0;
#pragma unroll
  for (int k = 0; k < 4; ++k)
    if (k < w) woff += wt[k];
  int pos = part[blockIdx.x] + woff + ex;
#pragma unroll
  for (int k = 0; k < 4; ++k) {
    int idx = base + k;
    if (idx < n) out[idx] = pos;
    pos += c[k];
  }
}

// ---- fused gather+final (3 dst types per dispatch, h updated in place) ------
// 3-way merged gather loop: one load per active relation per iteration ->
// 3 independent srcs->g chains in flight; 1/deg folded into the fmaf.
struct GFType {
  const ushort* g0; const ushort* g1; const ushort* g2;
  const ushort* t;  ushort* h;
  const float* bls; const float* lng; const float* lnb;
  int b0, b1, b2, nrel, ndst;
};
struct GFPack { GFType t[3]; };

__global__ __launch_bounds__(256) void gf_kernel(GFPack pk, const int* __restrict__ srcs,
                                                 const int* __restrict__ off) {
  GFType ty = (blockIdx.y == 0) ? pk.t[0] : (blockIdx.y == 1) ? pk.t[1] : pk.t[2];
  const int l8 = threadIdx.x & 7;
  const int d = (blockIdx.x * blockDim.x + threadIdx.x) >> 3;
  if (d >= ty.ndst) return;
  // hoist all relation ranges (independent loads issue together)
  int ja = off[ty.b0 + d], e1a = off[ty.b0 + d + 1];
  int jb = 0, e1b = 0, jc = 0, e1c = 0;
  if (ty.nrel > 1) { jb = off[ty.b1 + d]; e1b = off[ty.b1 + d + 1]; }
  if (ty.nrel > 2) { jc = off[ty.b2 + d]; e1c = off[ty.b2 + d + 1]; }
  const float ia = 1.f / fmaxf((float)(e1a - ja), 1.f);
  const float ib = 1.f / fmaxf((float)(e1b - jb), 1.f);
  const float ic = 1.f / fmaxf((float)(e1c - jc), 1.f);
  float blr[8], ggr[8], bbr[8];
  *(float4*)(blr)     = *(const float4*)(ty.bls + l8 * 8);
  *(float4*)(blr + 4) = *(const float4*)(ty.bls + l8 * 8 + 4);
  *(float4*)(ggr)     = *(const float4*)(ty.lng + l8 * 8);
  *(float4*)(ggr + 4) = *(const float4*)(ty.lng + l8 * 8 + 4);
  *(float4*)(bbr)     = *(const float4*)(ty.lnb + l8 * 8);
  *(float4*)(bbr + 4) = *(const float4*)(ty.lnb + l8 * 8 + 4);
  float o[8];
#pragma unroll
  for (int c = 0; c < 8; ++c) o[c] = 0.f;
  while (ja < e1a || jb < e1b || jc < e1c) {
    bool pa = ja < e1a, pb = jb < e1b, pc = jc < e1c;
    bf8_t va, vb, vc;
    if (pa) { int s = srcs[ja]; va = *(const bf8_t*)(ty.g0 + (size_t)s * 64 + l8 * 8); }
    if (pb) { int s = srcs[jb]; vb = *(const bf8_t*)(ty.g1 + (size_t)s * 64 + l8 * 8); }
    if (pc) { int s = srcs[jc]; vc = *(const bf8_t*)(ty.g2 + (size_t)s * 64 + l8 * 8); }
    if (pa) {
#pragma unroll
      for (int c = 0; c < 8; ++c) o[c] = fmaf(u2f((ushort)va[c]), ia, o[c]);
      ++ja;
    }
    if (pb) {
#pragma unroll
      for (int c = 0; c < 8; ++c) o[c] = fmaf(u2f((ushort)vb[c]), ib, o[c]);
      ++jb;
    }
    if (pc) {
#pragma unroll
      for (int c = 0; c < 8; ++c) o[c] = fmaf(u2f((ushort)vc[c]), ic, o[c]);
      ++jc;
    }
  }
  bf8_t tv = *(const bf8_t*)(ty.t + (size_t)d * 64 + l8 * 8);
  bf8_t hv = *(const bf8_t*)(ty.h + (size_t)d * 64 + l8 * 8);
  float v[8];
  float s = 0.f;
#pragma unroll
  for (int c = 0; c < 8; ++c) {
    float x = u2f((ushort)hv[c]) + fmaxf(o[c] + u2f((ushort)tv[c]) + blr[c], 0.f);
    v[c] = x;
    s += x;
  }
  s += __shfl_xor(s, 1, 64);
  s += __shfl_xor(s, 2, 64);
  s += __shfl_xor(s, 4, 64);
  float m = s * (1.f / 64.f);
  float vs = 0.f;
#pragma unroll
  for (int c = 0; c < 8; ++c) {
    float dd = v[c] - m;
    vs += dd * dd;
  }
  vs += __shfl_xor(vs, 1, 64);
  vs += __shfl_xor(vs, 2, 64);
  vs += __shfl_xor(vs, 4, 64);
  float rstd = rsqrtf(vs * (1.f / 64.f) + 1e-5f);
  bf8_t outv;
#pragma unroll
  for (int c = 0; c < 8; ++c)
    outv[c] = (short)f2bf((v[c] - m) * rstd * ggr[c] + bbr[c]);
  *(bf8_t*)(ty.h + (size_t)d * 64 + l8 * 8) = outv;   // in place
}

// ---------------- pool: 256 threads, bf8 loads, wave shfl reduce -------------
struct PoolArgs {
  const ushort* h0; const ushort* h1; const ushort* h2;
  const int* b0; const int* b1; const int* b2;
  int n0, n1, n2;
};

__global__ __launch_bounds__(256) void pool_kernel(PoolArgs a, float* __restrict__ out) {
  int ty = blockIdx.y;
  const ushort* h = (ty == 0) ? a.h0 : (ty == 1) ? a.h1 : a.h2;
  const int* batch = (ty == 0) ? a.b0 : (ty == 1) ? a.b1 : a.b2;
  int n = (ty == 0) ? a.n0 : (ty == 1) ? a.n1 : a.n2;
  int col_base = ty * 64;
  int gph = blockIdx.x >> 2;             // POOL_SPLIT = 4
  int s = blockIdx.x & 3;
  int lo = 0, hi = n;
  while (lo < hi) { int mid = (lo + hi) >> 1; if (batch[mid] < gph) lo = mid + 1; else hi = mid; }
  int beg = lo;
  hi = n;
  while (lo < hi) { int mid = (lo + hi) >> 1; if (batch[mid] < gph + 1) lo = mid + 1; else hi = mid; }
  int end = lo;
  int cnt = end - beg;
  if (cnt <= 0) return;
  int per = (cnt + POOL_SPLIT - 1) >> 2;
  int rb = beg + s * per;
  int re = min(rb + per, end);
  if (rb >= re) return;
  const int l8 = threadIdx.x & 7;
  const int grp = threadIdx.x >> 3;
  float o[8];
#pragma unroll
  for (int c = 0; c < 8; ++c) o[c] = 0.f;
  for (int r = rb + grp; r < re; r += 32) {
    bf8_t v = *(const bf8_t*)(h + (size_t)r * 64 + l8 * 8);
#pragma unroll
    for (int c = 0; c < 8; ++c) o[c] += u2f((ushort)v[c]);
  }
#pragma unroll
  for (int c = 0; c < 8; ++c) {
    o[c] += __shfl_xor(o[c], 8, 64);
    o[c] += __shfl_xor(o[c], 16, 64);
    o[c] += __shfl_xor(o[c], 32, 64);
  }
  if ((threadIdx.x & 56) == 0) {
#pragma unroll
    for (int c = 0; c < 8; ++c)
      unsafeAtomicAdd(out + gph * 192 + col_base + l8 * 8 + c, o[c]);
  }
}

__global__ __launch_bounds__(256) void pool_scale_kernel(
    float* __restrict__ out, const int* __restrict__ bp,
    const int* __restrict__ be, const int* __restrict__ bf,
    int np, int ne, int nf) {
  int idx = blockIdx.x * blockDim.x + threadIdx.x;
  if (idx >= 64 * 192) return;
  int gph = idx / 192, col = idx % 192;
  const int* b;
  int n;
  if (col < 64) { b = bp; n = np; }
  else if (col < 128) { b = be; n = ne; }
  else { b = bf; n = nf; }
  int lo = 0, hi = n;
  while (lo < hi) { int mid = (lo + hi) >> 1; if (b[mid] < gph) lo = mid + 1; else hi = mid; }
  int beg = lo;
  hi = n;
  while (lo < hi) { int mid = (lo + hi) >> 1; if (b[mid] < gph + 1) lo = mid + 1; else hi = mid; }
  int cnt = lo - beg;
  out[idx] = out[idx] / fmaxf((float)cnt, 1.f);
}

extern "C" void kernel_launch(void* const* d_in, const int* in_sizes, int n_in,
                              void* d_out, int out_size, void* d_ws, size_t ws_size,
                              hipStream_t stream) {
  const float* point_x = (const float*)d_in[0];
  const float* edge_x  = (const float*)d_in[1];
  const float* face_x  = (const float*)d_in[2];
  const int* bp = (const int*)d_in[3];
  const int* be = (const int*)d_in[4];
  const int* bf = (const int*)d_in[5];
  const int NP = in_sizes[3], NE = in_sizes[4], NF = in_sizes[5];
  const int Eg = in_sizes[6] / 2;

  const float* Wl  = (const float*)d_in[26];
  const float* blp = (const float*)d_in[27];
  const float* Wr  = (const float*)d_in[28];
  const float* lng = (const float*)d_in[29];
  const float* lnb = (const float*)d_in[30];

  // relations: 0 pp 1 fp 2 ep (dst P) | 3 pf 4 ef 5 ff (dst F) | 6 pe 7 fe (dst E)
  int nsrc[8] = {NP, NF, NE, NP, NE, NF, NP, NF};
  int ndst[8] = {NP, NP, NP, NF, NF, NF, NE, NE};
  int base[8], gb[8];
  base[0] = 0; gb[0] = 0;
  for (int r = 1; r < 8; ++r) {
    base[r] = base[r - 1] + ndst[r - 1];
    gb[r] = gb[r - 1] + nsrc[r - 1];
  }
  const size_t GROWS = (size_t)gb[7] + nsrc[7];          // 950k rows
  const int NDSUM = 3 * NP + 3 * NF + 2 * NE;

  // ---- workspace layout (~232 MB) ----
  char* p = (char*)d_ws;
  ushort* hA = (ushort*)p; p += (size_t)(NP + NE + NF) * 64 * 2;   // 44.8 MB
  ushort* g_all = (ushort*)p; p += GROWS * 64 * 2;                  // 121.6 MB
  ushort* t_all = (ushort*)p; p += (size_t)(NP + NE + NF) * 64 * 2; // 44.8 MB
  ushort* fw = (ushort*)p; p += (size_t)25 * 4096 * 2;
  float* bls = (float*)p; p += 6 * 64 * 4;
  int* srcs = (int*)p; p += (size_t)8 * Eg * 4;                     // 16 MB
  int* off = (int*)p; p += (size_t)(NDSUM + 1) * 4;
  const int nblk = (Eg + ABLK - 1) / ABLK;
  const int NCNT = 8 * NBUCK * nblk;
  int* counts = (int*)p; p += (size_t)NCNT * 4;
  int* coff = (int*)p; p += (size_t)(NCNT + 1) * 4;
  int* part = (int*)p; p += 4096;
  int2* bed = (int2*)g_all;  // 32 MB alias; dead before any GEMM writes g_all

  ushort* hp_ = hA;
  ushort* he_ = hA + (size_t)NP * 64;
  ushort* hf_ = hA + (size_t)(NP + NE) * 64;
  ushort* tP = t_all;
  ushort* tE = t_all + (size_t)NP * 64;
  ushort* tF = t_all + (size_t)(NP + NE) * 64;

  const int* ei[8] = {(const int*)d_in[6],  (const int*)d_in[7],
                      (const int*)d_in[8],  (const int*)d_in[9],
                      (const int*)d_in[10], (const int*)d_in[11],
                      (const int*)d_in[12], (const int*)d_in[13]};
  EIPack ep;
  ep.e0 = ei[0]; ep.e1 = ei[1]; ep.e2 = ei[2]; ep.e3 = ei[3];
  ep.e4 = ei[4]; ep.e5 = ei[5]; ep.e6 = ei[6]; ep.e7 = ei[7];
  ep.b0 = base[0]; ep.b1 = base[1]; ep.b2 = base[2]; ep.b3 = base[3];
  ep.b4 = base[4]; ep.b5 = base[5]; ep.b6 = base[6]; ep.b7 = base[7];

  // ---- CSR build ----
  binA1_kernel<<<8 * nblk, 256, 0, stream>>>(ep, counts, Eg, nblk);
  const int nb = (NCNT + 1023) / 1024;
  scan1_kernel<<<nb, 256, 0, stream>>>(counts, part, NCNT);
  scan2_kernel<<<1, 1024, 0, stream>>>(part, coff, nb, NCNT, 8 * Eg);
  scan3_kernel<<<nb, 256, 0, stream>>>(counts, part, coff, NCNT);
  binA2_kernel<<<8 * nblk, 256, 0, stream>>>(ep, coff, bed, Eg, nblk);
  binB_kernel<<<8 * NBUCK, 256, 0, stream>>>(coff, bed, off, srcs,
                                             nblk, NP, NF, NE, 8 * Eg);

  // ---- weight prep ----
  prep_kernel<<<(25 * 4096 + 6 * 64 + 255) / 256, 256, 0, stream>>>(
      Wl, Wr, blp, (const float*)d_in[16], (const float*)d_in[20],
      (const float*)d_in[24], fw, bls);

  auto gblk = [](int n) { return ((n + 31) / 32 + 3) / 4; };

  // ---- input MLPs: stage1 (merged) into g_all scratch, stage2 MFMA -> hA ----
  ushort* sp = g_all;
  ushort* se = g_all + (size_t)NP * 64;
  ushort* sf = g_all + (size_t)(NP + NE) * 64;
  MLPack ma;
  ma.j[0] = {point_x, (const float*)d_in[14], (const float*)d_in[15], sp, NP};
  ma.j[1] = {edge_x,  (const float*)d_in[18], (const float*)d_in[19], se, NE};
  ma.j[2] = {face_x,  (const float*)d_in[22], (const float*)d_in[23], sf, NF};
  mlp1_kernel<<<dim3(512, 3), 256, 0, stream>>>(ma);

  GJobs12 init{};
  init.j[0] = {sp, fw + 22 * 4096, (const float*)d_in[17], hp_, NP};
  init.j[1] = {se, fw + 23 * 4096, (const float*)d_in[21], he_, NE};
  init.j[2] = {sf, fw + 24 * 4096, (const float*)d_in[25], hf_, NF};
  gemm_multi_kernel<<<dim3(gblk(NP), 3), 256, 0, stream>>>(init);

  const ushort* hsrc[8] = {hp_, hf_, he_, hp_, he_, hf_, hp_, hf_};
  const int gfx = (NP * 8 + 255) / 256;

  // ---- 2 hetero-SAGE layers: ONE gemm dispatch + ONE gf dispatch each ----
  for (int i = 0; i < 2; ++i) {
    GJobs12 js{};
    for (int r = 0; r < 8; ++r)
      js.j[r] = {hsrc[r], fw + (size_t)(i * 8 + r) * 4096, nullptr,
                 g_all + (size_t)gb[r] * 64, nsrc[r]};
    js.j[8]  = {hp_, fw + (size_t)(16 + i * 3 + 0) * 4096, nullptr, tP, NP};
    js.j[9]  = {he_, fw + (size_t)(16 + i * 3 + 1) * 4096, nullptr, tE, NE};
    js.j[10] = {hf_, fw + (size_t)(16 + i * 3 + 2) * 4096, nullptr, tF, NF};
    gemm_multi_kernel<<<dim3(gblk(NP), 11), 256, 0, stream>>>(js);

    GFPack pk;
    pk.t[0] = {g_all + (size_t)gb[0] * 64, g_all + (size_t)gb[1] * 64,
               g_all + (size_t)gb[2] * 64, tP, hp_,
               bls + (i * 3 + 0) * 64, lng + (i * 3 + 0) * 64, lnb + (i * 3 + 0) * 64,
               base[0], base[1], base[2], 3, NP};
    pk.t[1] = {g_all + (size_t)gb[3] * 64, g_all + (size_t)gb[4] * 64,
               g_all + (size_t)gb[5] * 64, tF, hf_,
               bls + (i * 3 + 2) * 64, lng + (i * 3 + 2) * 64, lnb + (i * 3 + 2) * 64,
               base[3], base[4], base[5], 3, NF};
    pk.t[2] = {g_all + (size_t)gb[6] * 64, g_all + (size_t)gb[7] * 64,
               g_all + (size_t)gb[6] * 64, tE, he_,
               bls + (i * 3 + 1) * 64, lng + (i * 3 + 1) * 64, lnb + (i * 3 + 1) * 64,
               base[6], base[7], 0, 2, NE};
    gf_kernel<<<dim3(gfx, 3), 256, 0, stream>>>(pk, srcs, off);
  }

  // ---- pool + scale ----
  float* out = (float*)d_out;
  hipMemsetAsync(out, 0, (size_t)out_size * sizeof(float), stream);
  PoolArgs pa;
  pa.h0 = hp_; pa.h1 = he_; pa.h2 = hf_;
  pa.b0 = bp; pa.b1 = be; pa.b2 = bf;
  pa.n0 = NP; pa.n1 = NE; pa.n2 = NF;
  pool_kernel<<<dim3(64 * POOL_SPLIT, 3), 256, 0, stream>>>(pa, out);
  pool_scale_kernel<<<(64 * 192 + 255) / 256, 256, 0, stream>>>(out, bp, be, bf, NP, NE, NF);
}

// Round 13
// 480.124 us; speedup vs baseline: 1.2564x; 1.2564x over previous
//
#include <hip/hip_runtime.h>
#include <hip/hip_bf16.h>

// CADTopoEncoder: hetero-GNN (point/edge/face), 2 SAGE layers + LN + pool.
// bf16 hidden state (in place); mfma_f32_16x16x32_bf16 for all 64x64 matmuls
// (one 11-job dispatch/layer); merged gf dispatch (3 dst types), sequential
// per-relation gather loops (r11-proven; r12's merged loop diverged and lost).
// CSR build: two-level counting sort with PACKED (dloc<<18|src) bin entries.

#define POOL_SPLIT 4
#define NBUCK 49
#define ABLK 4096

typedef __attribute__((ext_vector_type(8))) short bf8_t;   // 8 bf16 in 4 VGPRs
typedef __attribute__((ext_vector_type(4))) float f32x4;

__device__ __forceinline__ ushort f2bf(float f) {
  union { __hip_bfloat16 b; ushort u; } v;
  v.b = __float2bfloat16(f);
  return v.u;
}
__device__ __forceinline__ float u2f(ushort u) {
  union { ushort u; __hip_bfloat16 b; } v;
  v.u = u;
  return __bfloat162float(v.b);
}

// ---------------- prep: weights -> bf16 MFMA fragment order, summed biases ----
__global__ __launch_bounds__(256) void prep_kernel(
    const float* __restrict__ Wl, const float* __restrict__ Wr,
    const float* __restrict__ bl, const float* __restrict__ w2p,
    const float* __restrict__ w2e, const float* __restrict__ w2f,
    ushort* __restrict__ fw, float* __restrict__ bls) {
  int idx = blockIdx.x * blockDim.x + threadIdx.x;
  if (idx < 25 * 4096) {
    int m = idx >> 12, e = idx & 4095;
    int i8 = e >> 3, b = e & 7;
    int lane = i8 & 63, cb = i8 >> 6;
    int ks = cb & 1, ct = cb >> 1;
    int k = ks * 32 + ((lane >> 4) << 3) + b;
    int col = (ct << 4) + (lane & 15);
    int widx = (k << 6) + col;
    float v;
    if (m < 16) {
      v = Wl[(size_t)m * 4096 + widx];
    } else if (m < 22) {
      int c = m - 16, i = c / 3, t = c % 3;
      int rb = (t == 0) ? 0 : ((t == 1) ? 6 : 3);
      int rc = (t == 1) ? 2 : 3;
      v = 0.f;
      for (int r = 0; r < rc; ++r) v += Wr[(size_t)(i * 8 + rb + r) * 4096 + widx];
    } else {
      const float* w2 = (m == 22) ? w2p : ((m == 23) ? w2e : w2f);
      v = w2[widx];
    }
    fw[idx] = f2bf(v);
  } else if (idx < 25 * 4096 + 6 * 64) {
    int j = idx - 25 * 4096;
    int c = j >> 6, e = j & 63;
    int i = c / 3, t = c % 3;
    int rb = (t == 0) ? 0 : ((t == 1) ? 6 : 3);
    int rc = (t == 1) ? 2 : 3;
    float s = 0.f;
    for (int r = 0; r < rc; ++r) s += bl[(i * 8 + rb + r) * 64 + e];
    bls[c * 64 + e] = s;
  }
}

// ---------------- batched MFMA GEMM: up to 12 jobs per dispatch --------------
struct GJob { const ushort* A; const ushort* W; const float* bias; ushort* C; int n; };
struct GJobs12 { GJob j[12]; };

__device__ __forceinline__ GJob gsel(const GJobs12& js, int y) {
  switch (y) {
    case 0: return js.j[0];  case 1: return js.j[1];  case 2: return js.j[2];
    case 3: return js.j[3];  case 4: return js.j[4];  case 5: return js.j[5];
    case 6: return js.j[6];  case 7: return js.j[7];  case 8: return js.j[8];
    case 9: return js.j[9];  case 10: return js.j[10]; default: return js.j[11];
  }
}

__global__ __launch_bounds__(256) void gemm_multi_kernel(GJobs12 js) {
  GJob jb = gsel(js, blockIdx.y);
  const int n = jb.n;
  const int lane = threadIdx.x & 63;
  const int wid = (blockIdx.x * blockDim.x + threadIdx.x) >> 6;
  const int r0 = wid * 32;
  if (r0 >= n) return;
  bf8_t bw[8];
#pragma unroll
  for (int i = 0; i < 8; ++i)
    bw[i] = *(const bf8_t*)(jb.W + ((i << 6) + lane) * 8);
  const int koff = ((lane >> 4) << 3);
  int ra = r0 + (lane & 15);
  int rb = ra + 16;
  ra = min(ra, n - 1);
  rb = min(rb, n - 1);
  const bf8_t a00 = *(const bf8_t*)(jb.A + (size_t)ra * 64 + koff);
  const bf8_t a01 = *(const bf8_t*)(jb.A + (size_t)ra * 64 + 32 + koff);
  const bf8_t a10 = *(const bf8_t*)(jb.A + (size_t)rb * 64 + koff);
  const bf8_t a11 = *(const bf8_t*)(jb.A + (size_t)rb * 64 + 32 + koff);
  f32x4 acc[8];
#pragma unroll
  for (int i = 0; i < 8; ++i) acc[i] = (f32x4){0.f, 0.f, 0.f, 0.f};
#pragma unroll
  for (int ct = 0; ct < 4; ++ct) {
    acc[ct]     = __builtin_amdgcn_mfma_f32_16x16x32_bf16(a00, bw[ct * 2 + 0], acc[ct], 0, 0, 0);
    acc[ct]     = __builtin_amdgcn_mfma_f32_16x16x32_bf16(a01, bw[ct * 2 + 1], acc[ct], 0, 0, 0);
    acc[4 + ct] = __builtin_amdgcn_mfma_f32_16x16x32_bf16(a10, bw[ct * 2 + 0], acc[4 + ct], 0, 0, 0);
    acc[4 + ct] = __builtin_amdgcn_mfma_f32_16x16x32_bf16(a11, bw[ct * 2 + 1], acc[4 + ct], 0, 0, 0);
  }
  float bv[4] = {0.f, 0.f, 0.f, 0.f};
  if (jb.bias) {
#pragma unroll
    for (int ct = 0; ct < 4; ++ct) bv[ct] = jb.bias[ct * 16 + (lane & 15)];
  }
  const int rowb = r0 + ((lane >> 4) << 2);
  const int cb = lane & 15;
#pragma unroll
  for (int rt = 0; rt < 2; ++rt) {
#pragma unroll
    for (int q = 0; q < 4; ++q) {
      int row = rowb + rt * 16 + q;
      if (row < n) {
#pragma unroll
        for (int ct = 0; ct < 4; ++ct)
          jb.C[(size_t)row * 64 + ct * 16 + cb] = f2bf(acc[rt * 4 + ct][q] + bv[ct]);
      }
    }
  }
}

// ---------------- mlp stage 1 (3 types in one dispatch) ----------------------
template <int FIN>
__device__ __forceinline__ void mlp1_body(
    const float* __restrict__ x, const float* __restrict__ w1,
    const float* __restrict__ b1, ushort* __restrict__ h1, int n) {
  const int lane = threadIdx.x & 63;
  int wid = (blockIdx.x * blockDim.x + threadIdx.x) >> 6;
  const int nw = (gridDim.x * blockDim.x) >> 6;
  float w1c[FIN];
#pragma unroll
  for (int k = 0; k < FIN; ++k) w1c[k] = w1[k * 64 + lane];
  const float b1v = b1[lane];
  for (int r = wid; r < n; r += nw) {
    float s = b1v;
#pragma unroll
    for (int k = 0; k < FIN; ++k) s = fmaf(x[(size_t)r * FIN + k], w1c[k], s);
    h1[(size_t)r * 64 + lane] = f2bf(fmaxf(s, 0.f));
  }
}

struct MLPJob { const float* x; const float* w1; const float* b1; ushort* o; int n; };
struct MLPack { MLPJob j[3]; };

__global__ __launch_bounds__(256) void mlp1_kernel(MLPack a) {
  if (blockIdx.y == 0)      mlp1_body<3>(a.j[0].x, a.j[0].w1, a.j[0].b1, a.j[0].o, a.j[0].n);
  else if (blockIdx.y == 1) mlp1_body<2>(a.j[1].x, a.j[1].w1, a.j[1].b1, a.j[1].o, a.j[1].n);
  else                      mlp1_body<16>(a.j[2].x, a.j[2].w1, a.j[2].b1, a.j[2].o, a.j[2].n);
}

// ---------------- CSR build: two-level counting sort (packed entries) --------
struct EIPack {
  const int* e0; const int* e1; const int* e2; const int* e3;
  const int* e4; const int* e5; const int* e6; const int* e7;
  int b0, b1, b2, b3, b4, b5, b6, b7;
};

__device__ __forceinline__ void ei_sel(const EIPack& t, int r, const int*& ei, int& b) {
  switch (r) {
    case 0: ei = t.e0; b = t.b0; break;
    case 1: ei = t.e1; b = t.b1; break;
    case 2: ei = t.e2; b = t.b2; break;
    case 3: ei = t.e3; b = t.b3; break;
    case 4: ei = t.e4; b = t.b4; break;
    case 5: ei = t.e5; b = t.b5; break;
    case 6: ei = t.e6; b = t.b6; break;
    default: ei = t.e7; b = t.b7; break;
  }
}

__device__ __forceinline__ int rel_shift(int rel) {
  return rel < 3 ? 12 : (rel < 6 ? 10 : 11);  // P:4096, F:1024, E:2048 dsts/bucket
}

__global__ __launch_bounds__(256) void binA1_kernel(EIPack t, int* __restrict__ counts,
                                                    int E, int nblk) {
  __shared__ int hist[NBUCK];
  int rel = blockIdx.x % 8, blk = blockIdx.x / 8;
  const int* ei; int bb;
  ei_sel(t, rel, ei, bb);
  int shift = rel_shift(rel);
  for (int i = threadIdx.x; i < NBUCK; i += 256) hist[i] = 0;
  __syncthreads();
  int e0 = blk * ABLK;
  for (int i = threadIdx.x; i < ABLK; i += 256) {
    int e = e0 + i;
    if (e < E) {
      int d = __builtin_nontemporal_load(ei + E + e);
      atomicAdd(&hist[d >> shift], 1);
    }
  }
  __syncthreads();
  for (int i = threadIdx.x; i < NBUCK; i += 256)
    counts[(rel * NBUCK + i) * nblk + blk] = hist[i];
}

// A2: place PACKED (dloc<<18 | src) into bucket-major array (4B/edge).
__global__ __launch_bounds__(256) void binA2_kernel(EIPack t, const int* __restrict__ coff,
                                                    int* __restrict__ bed,
                                                    int E, int nblk) {
  __shared__ int cur[NBUCK];
  int rel = blockIdx.x % 8, blk = blockIdx.x / 8;
  const int* ei; int bb;
  ei_sel(t, rel, ei, bb);
  int shift = rel_shift(rel);
  int lmask = (1 << shift) - 1;
  for (int i = threadIdx.x; i < NBUCK; i += 256)
    cur[i] = coff[(rel * NBUCK + i) * nblk + blk];
  __syncthreads();
  int e0 = blk * ABLK;
  for (int i = threadIdx.x; i < ABLK; i += 256) {
    int e = e0 + i;
    if (e < E) {
      int s = __builtin_nontemporal_load(ei + e);
      int d = __builtin_nontemporal_load(ei + E + e);
      int p = atomicAdd(&cur[d >> shift], 1);
      bed[p] = ((d & lmask) << 18) | s;
    }
  }
}

__global__ __launch_bounds__(256) void binB_kernel(const int* __restrict__ coff,
                                                   const int* __restrict__ bed,
                                                   int* __restrict__ off,
                                                   int* __restrict__ srcs,
                                                   int nblk, int NP_, int NF_, int NE_,
                                                   int Etot) {
  __shared__ int hist[4096];
  __shared__ int wsum[4];
  int gb = blockIdx.x;                    // 0..8*NBUCK-1
  int rel = gb / NBUCK, b = gb % NBUCK;
  int shift = rel_shift(rel);
  int D = 1 << shift;
  int ndst_r = rel < 3 ? NP_ : (rel < 6 ? NF_ : NE_);
  int rbase = rel < 3 ? rel * NP_
            : (rel < 6 ? 3 * NP_ + (rel - 3) * NF_
                       : 3 * NP_ + 3 * NF_ + (rel - 6) * NE_);
  int d0 = b << shift;
  int Dl = min(D, ndst_r - d0);
  int ebase = coff[gb * nblk];
  int eend  = coff[(gb + 1) * nblk];
  for (int i = threadIdx.x; i < D; i += 256) hist[i] = 0;
  __syncthreads();
  for (int e = ebase + threadIdx.x; e < eend; e += 256)
    atomicAdd(&hist[bed[e] >> 18], 1);
  __syncthreads();
  const int PT = D >> 8;
  int tbase = threadIdx.x * PT;
  int ts = 0;
  for (int k = 0; k < PT; ++k) ts += hist[tbase + k];
  int lane = threadIdx.x & 63, w = threadIdx.x >> 6;
  int x = ts;
#pragma unroll
  for (int dd = 1; dd < 64; dd <<= 1) {
    int y = __shfl_up(x, dd, 64);
    if (lane >= dd) x += y;
  }
  if (lane == 63) wsum[w] = x;
  __syncthreads();
  int woff = 0;
#pragma unroll
  for (int k = 0; k < 4; ++k)
    if (k < w) woff += wsum[k];
  int pos = woff + x - ts;
  for (int k = 0; k < PT; ++k) {
    int c = hist[tbase + k];
    hist[tbase + k] = pos;
    if (tbase + k < Dl) off[rbase + d0 + tbase + k] = ebase + pos;
    pos += c;
  }
  __syncthreads();
  for (int e = ebase + threadIdx.x; e < eend; e += 256) {
    int w_ = bed[e];
    int p = atomicAdd(&hist[w_ >> 18], 1);
    srcs[ebase + p] = w_ & 0x3FFFF;
  }
  if (gb == 0 && threadIdx.x == 0)
    off[3 * NP_ + 3 * NF_ + 2 * NE_] = Etot;
}

__global__ __launch_bounds__(256) void scan1_kernel(const int* __restrict__ cnt,
                                                    int* __restrict__ part, int n) {
  __shared__ int wt[4];
  int base = blockIdx.x * 1024;
  int t = 0;
  for (int i = threadIdx.x; i < 1024; i += 256) {
    int idx = base + i;
    if (idx < n) t += cnt[idx];
  }
#pragma unroll
  for (int d = 32; d > 0; d >>= 1) t += __shfl_xor(t, d, 64);
  if ((threadIdx.x & 63) == 0) wt[threadIdx.x >> 6] = t;
  __syncthreads();
  if (threadIdx.x == 0) part[blockIdx.x] = wt[0] + wt[1] + wt[2] + wt[3];
}

__global__ __launch_bounds__(1024) void scan2_kernel(int* __restrict__ part,
                                                     int* __restrict__ off, int nb,
                                                     int n, int total) {
  __shared__ int lds[1024];
  int tid = threadIdx.x;
  int v = (tid < nb) ? part[tid] : 0;
  lds[tid] = v;
  __syncthreads();
  for (int d = 1; d < 1024; d <<= 1) {
    int y = (tid >= d) ? lds[tid - d] : 0;
    __syncthreads();
    lds[tid] += y;
    __syncthreads();
  }
  if (tid < nb) part[tid] = lds[tid] - v;  // exclusive
  if (tid == 0) off[n] = total;
}

__global__ __launch_bounds__(256) void scan3_kernel(const int* cnt,
                                                    const int* __restrict__ part,
                                                    int* __restrict__ out, int n) {
  __shared__ int wt[4];
  int base = blockIdx.x * 1024 + threadIdx.x * 4;
  int c[4];
#pragma unroll
  for (int k = 0; k < 4; ++k) {
    int idx = base + k;
    c[k] = (idx < n) ? cnt[idx] : 0;
  }
  int t = c[0] + c[1] + c[2] + c[3];
  int lane = threadIdx.x & 63, w = threadIdx.x >> 6;
  int x = t;
#pragma unroll
  for (int d = 1; d < 64; d <<= 1) {
    int y = __shfl_up(x, d, 64);
    if (lane >= d) x += y;
  }
  int ex = x - t;
  if (lane == 63) wt[w] = x;
  __syncthreads();
  int woff = 0;
#pragma unroll
  for (int k = 0; k < 4; ++k)
    if (k < w) woff += wt[k];
  int pos = part[blockIdx.x] + woff + ex;
#pragma unroll
  for (int k = 0; k < 4; ++k) {
    int idx = base + k;
    if (idx < n) out[idx] = pos;
    pos += c[k];
  }
}

// ---- fused gather+final (3 dst types per dispatch, h updated in place) ------
// r11-proven structure: hoisted off-ranges, SEQUENTIAL per-relation gathers
// with x2 unroll (uniform control flow; r12's merged loop diverged and lost).
__device__ __forceinline__ void gather_rel(const ushort* __restrict__ g,
    const int* __restrict__ srcs, int e0, int e1, int l8, float o[8]) {
  float t8[8];
#pragma unroll
  for (int c = 0; c < 8; ++c) t8[c] = 0.f;
  int j = e0;
  for (; j + 2 <= e1; j += 2) {
    int s0 = srcs[j], s1 = srcs[j + 1];
    bf8_t v0 = *(const bf8_t*)(g + (size_t)s0 * 64 + l8 * 8);
    bf8_t v1 = *(const bf8_t*)(g + (size_t)s1 * 64 + l8 * 8);
#pragma unroll
    for (int c = 0; c < 8; ++c) t8[c] += u2f((ushort)v0[c]) + u2f((ushort)v1[c]);
  }
  if (j < e1) {
    int s = srcs[j];
    bf8_t v = *(const bf8_t*)(g + (size_t)s * 64 + l8 * 8);
#pragma unroll
    for (int c = 0; c < 8; ++c) t8[c] += u2f((ushort)v[c]);
  }
  float inv = 1.f / fmaxf((float)(e1 - e0), 1.f);
#pragma unroll
  for (int c = 0; c < 8; ++c) o[c] = fmaf(t8[c], inv, o[c]);
}

struct GFType {
  const ushort* g0; const ushort* g1; const ushort* g2;
  const ushort* t;  ushort* h;
  const float* bls; const float* lng; const float* lnb;
  int b0, b1, b2, nrel, ndst;
};
struct GFPack { GFType t[3]; };

__global__ __launch_bounds__(256) void gf_kernel(GFPack pk, const int* __restrict__ srcs,
                                                 const int* __restrict__ off) {
  GFType ty = (blockIdx.y == 0) ? pk.t[0] : (blockIdx.y == 1) ? pk.t[1] : pk.t[2];
  const int l8 = threadIdx.x & 7;
  const int d = (blockIdx.x * blockDim.x + threadIdx.x) >> 3;
  if (d >= ty.ndst) return;
  // hoist all relation ranges (independent loads issue together)
  int e0a = off[ty.b0 + d], e1a = off[ty.b0 + d + 1];
  int e0b = 0, e1b = 0, e0c = 0, e1c = 0;
  if (ty.nrel > 1) { e0b = off[ty.b1 + d]; e1b = off[ty.b1 + d + 1]; }
  if (ty.nrel > 2) { e0c = off[ty.b2 + d]; e1c = off[ty.b2 + d + 1]; }
  float blr[8], ggr[8], bbr[8];
  *(float4*)(blr)     = *(const float4*)(ty.bls + l8 * 8);
  *(float4*)(blr + 4) = *(const float4*)(ty.bls + l8 * 8 + 4);
  *(float4*)(ggr)     = *(const float4*)(ty.lng + l8 * 8);
  *(float4*)(ggr + 4) = *(const float4*)(ty.lng + l8 * 8 + 4);
  *(float4*)(bbr)     = *(const float4*)(ty.lnb + l8 * 8);
  *(float4*)(bbr + 4) = *(const float4*)(ty.lnb + l8 * 8 + 4);
  float o[8];
#pragma unroll
  for (int c = 0; c < 8; ++c) o[c] = 0.f;
  gather_rel(ty.g0, srcs, e0a, e1a, l8, o);
  if (ty.nrel > 1) gather_rel(ty.g1, srcs, e0b, e1b, l8, o);
  if (ty.nrel > 2) gather_rel(ty.g2, srcs, e0c, e1c, l8, o);
  bf8_t tv = *(const bf8_t*)(ty.t + (size_t)d * 64 + l8 * 8);
  bf8_t hv = *(const bf8_t*)(ty.h + (size_t)d * 64 + l8 * 8);
  float v[8];
  float s = 0.f;
#pragma unroll
  for (int c = 0; c < 8; ++c) {
    float x = u2f((ushort)hv[c]) + fmaxf(o[c] + u2f((ushort)tv[c]) + blr[c], 0.f);
    v[c] = x;
    s += x;
  }
  s += __shfl_xor(s, 1, 64);
  s += __shfl_xor(s, 2, 64);
  s += __shfl_xor(s, 4, 64);
  float m = s * (1.f / 64.f);
  float vs = 0.f;
#pragma unroll
  for (int c = 0; c < 8; ++c) {
    float dd = v[c] - m;
    vs += dd * dd;
  }
  vs += __shfl_xor(vs, 1, 64);
  vs += __shfl_xor(vs, 2, 64);
  vs += __shfl_xor(vs, 4, 64);
  float rstd = rsqrtf(vs * (1.f / 64.f) + 1e-5f);
  bf8_t outv;
#pragma unroll
  for (int c = 0; c < 8; ++c)
    outv[c] = (short)f2bf((v[c] - m) * rstd * ggr[c] + bbr[c]);
  *(bf8_t*)(ty.h + (size_t)d * 64 + l8 * 8) = outv;   // in place
}

// ---------------- pool: 256 threads, bf8 loads, wave shfl reduce -------------
struct PoolArgs {
  const ushort* h0; const ushort* h1; const ushort* h2;
  const int* b0; const int* b1; const int* b2;
  int n0, n1, n2;
};

__global__ __launch_bounds__(256) void pool_kernel(PoolArgs a, float* __restrict__ out) {
  int ty = blockIdx.y;
  const ushort* h = (ty == 0) ? a.h0 : (ty == 1) ? a.h1 : a.h2;
  const int* batch = (ty == 0) ? a.b0 : (ty == 1) ? a.b1 : a.b2;
  int n = (ty == 0) ? a.n0 : (ty == 1) ? a.n1 : a.n2;
  int col_base = ty * 64;
  int gph = blockIdx.x >> 2;             // POOL_SPLIT = 4
  int s = blockIdx.x & 3;
  int lo = 0, hi = n;
  while (lo < hi) { int mid = (lo + hi) >> 1; if (batch[mid] < gph) lo = mid + 1; else hi = mid; }
  int beg = lo;
  hi = n;
  while (lo < hi) { int mid = (lo + hi) >> 1; if (batch[mid] < gph + 1) lo = mid + 1; else hi = mid; }
  int end = lo;
  int cnt = end - beg;
  if (cnt <= 0) return;
  int per = (cnt + POOL_SPLIT - 1) >> 2;
  int rb = beg + s * per;
  int re = min(rb + per, end);
  if (rb >= re) return;
  const int l8 = threadIdx.x & 7;
  const int grp = threadIdx.x >> 3;
  float o[8];
#pragma unroll
  for (int c = 0; c < 8; ++c) o[c] = 0.f;
  for (int r = rb + grp; r < re; r += 32) {
    bf8_t v = *(const bf8_t*)(h + (size_t)r * 64 + l8 * 8);
#pragma unroll
    for (int c = 0; c < 8; ++c) o[c] += u2f((ushort)v[c]);
  }
#pragma unroll
  for (int c = 0; c < 8; ++c) {
    o[c] += __shfl_xor(o[c], 8, 64);
    o[c] += __shfl_xor(o[c], 16, 64);
    o[c] += __shfl_xor(o[c], 32, 64);
  }
  if ((threadIdx.x & 56) == 0) {
#pragma unroll
    for (int c = 0; c < 8; ++c)
      unsafeAtomicAdd(out + gph * 192 + col_base + l8 * 8 + c, o[c]);
  }
}

__global__ __launch_bounds__(256) void pool_scale_kernel(
    float* __restrict__ out, const int* __restrict__ bp,
    const int* __restrict__ be, const int* __restrict__ bf,
    int np, int ne, int nf) {
  int idx = blockIdx.x * blockDim.x + threadIdx.x;
  if (idx >= 64 * 192) return;
  int gph = idx / 192, col = idx % 192;
  const int* b;
  int n;
  if (col < 64) { b = bp; n = np; }
  else if (col < 128) { b = be; n = ne; }
  else { b = bf; n = nf; }
  int lo = 0, hi = n;
  while (lo < hi) { int mid = (lo + hi) >> 1; if (b[mid] < gph) lo = mid + 1; else hi = mid; }
  int beg = lo;
  hi = n;
  while (lo < hi) { int mid = (lo + hi) >> 1; if (b[mid] < gph + 1) lo = mid + 1; else hi = mid; }
  int cnt = lo - beg;
  out[idx] = out[idx] / fmaxf((float)cnt, 1.f);
}

extern "C" void kernel_launch(void* const* d_in, const int* in_sizes, int n_in,
                              void* d_out, int out_size, void* d_ws, size_t ws_size,
                              hipStream_t stream) {
  const float* point_x = (const float*)d_in[0];
  const float* edge_x  = (const float*)d_in[1];
  const float* face_x  = (const float*)d_in[2];
  const int* bp = (const int*)d_in[3];
  const int* be = (const int*)d_in[4];
  const int* bf = (const int*)d_in[5];
  const int NP = in_sizes[3], NE = in_sizes[4], NF = in_sizes[5];
  const int Eg = in_sizes[6] / 2;

  const float* Wl  = (const float*)d_in[26];
  const float* blp = (const float*)d_in[27];
  const float* Wr  = (const float*)d_in[28];
  const float* lng = (const float*)d_in[29];
  const float* lnb = (const float*)d_in[30];

  // relations: 0 pp 1 fp 2 ep (dst P) | 3 pf 4 ef 5 ff (dst F) | 6 pe 7 fe (dst E)
  int nsrc[8] = {NP, NF, NE, NP, NE, NF, NP, NF};
  int ndst[8] = {NP, NP, NP, NF, NF, NF, NE, NE};
  int base[8], gb[8];
  base[0] = 0; gb[0] = 0;
  for (int r = 1; r < 8; ++r) {
    base[r] = base[r - 1] + ndst[r - 1];
    gb[r] = gb[r - 1] + nsrc[r - 1];
  }
  const size_t GROWS = (size_t)gb[7] + nsrc[7];          // 950k rows
  const int NDSUM = 3 * NP + 3 * NF + 2 * NE;

  // ---- workspace layout (~232 MB) ----
  char* p = (char*)d_ws;
  ushort* hA = (ushort*)p; p += (size_t)(NP + NE + NF) * 64 * 2;   // 44.8 MB
  ushort* g_all = (ushort*)p; p += GROWS * 64 * 2;                  // 121.6 MB
  ushort* t_all = (ushort*)p; p += (size_t)(NP + NE + NF) * 64 * 2; // 44.8 MB
  ushort* fw = (ushort*)p; p += (size_t)25 * 4096 * 2;
  float* bls = (float*)p; p += 6 * 64 * 4;
  int* srcs = (int*)p; p += (size_t)8 * Eg * 4;                     // 16 MB
  int* off = (int*)p; p += (size_t)(NDSUM + 1) * 4;
  const int nblk = (Eg + ABLK - 1) / ABLK;
  const int NCNT = 8 * NBUCK * nblk;
  int* counts = (int*)p; p += (size_t)NCNT * 4;
  int* coff = (int*)p; p += (size_t)(NCNT + 1) * 4;
  int* part = (int*)p; p += 4096;
  int* bed = (int*)g_all;  // 16 MB alias; dead before any GEMM writes g_all

  ushort* hp_ = hA;
  ushort* he_ = hA + (size_t)NP * 64;
  ushort* hf_ = hA + (size_t)(NP + NE) * 64;
  ushort* tP = t_all;
  ushort* tE = t_all + (size_t)NP * 64;
  ushort* tF = t_all + (size_t)(NP + NE) * 64;

  const int* ei[8] = {(const int*)d_in[6],  (const int*)d_in[7],
                      (const int*)d_in[8],  (const int*)d_in[9],
                      (const int*)d_in[10], (const int*)d_in[11],
                      (const int*)d_in[12], (const int*)d_in[13]};
  EIPack ep;
  ep.e0 = ei[0]; ep.e1 = ei[1]; ep.e2 = ei[2]; ep.e3 = ei[3];
  ep.e4 = ei[4]; ep.e5 = ei[5]; ep.e6 = ei[6]; ep.e7 = ei[7];
  ep.b0 = base[0]; ep.b1 = base[1]; ep.b2 = base[2]; ep.b3 = base[3];
  ep.b4 = base[4]; ep.b5 = base[5]; ep.b6 = base[6]; ep.b7 = base[7];

  // ---- CSR build ----
  binA1_kernel<<<8 * nblk, 256, 0, stream>>>(ep, counts, Eg, nblk);
  const int nb = (NCNT + 1023) / 1024;
  scan1_kernel<<<nb, 256, 0, stream>>>(counts, part, NCNT);
  scan2_kernel<<<1, 1024, 0, stream>>>(part, coff, nb, NCNT, 8 * Eg);
  scan3_kernel<<<nb, 256, 0, stream>>>(counts, part, coff, NCNT);
  binA2_kernel<<<8 * nblk, 256, 0, stream>>>(ep, coff, bed, Eg, nblk);
  binB_kernel<<<8 * NBUCK, 256, 0, stream>>>(coff, bed, off, srcs,
                                             nblk, NP, NF, NE, 8 * Eg);

  // ---- weight prep ----
  prep_kernel<<<(25 * 4096 + 6 * 64 + 255) / 256, 256, 0, stream>>>(
      Wl, Wr, blp, (const float*)d_in[16], (const float*)d_in[20],
      (const float*)d_in[24], fw, bls);

  auto gblk = [](int n) { return ((n + 31) / 32 + 3) / 4; };

  // ---- input MLPs: stage1 (merged) into t_all scratch, stage2 MFMA -> hA ----
  ushort* sp = t_all;
  ushort* se = t_all + (size_t)NP * 64;
  ushort* sf = t_all + (size_t)(NP + NE) * 64;
  MLPack ma;
  ma.j[0] = {point_x, (const float*)d_in[14], (const float*)d_in[15], sp, NP};
  ma.j[1] = {edge_x,  (const float*)d_in[18], (const float*)d_in[19], se, NE};
  ma.j[2] = {face_x,  (const float*)d_in[22], (const float*)d_in[23], sf, NF};
  mlp1_kernel<<<dim3(512, 3), 256, 0, stream>>>(ma);

  GJobs12 init{};
  init.j[0] = {sp, fw + 22 * 4096, (const float*)d_in[17], hp_, NP};
  init.j[1] = {se, fw + 23 * 4096, (const float*)d_in[21], he_, NE};
  init.j[2] = {sf, fw + 24 * 4096, (const float*)d_in[25], hf_, NF};
  gemm_multi_kernel<<<dim3(gblk(NP), 3), 256, 0, stream>>>(init);

  const ushort* hsrc[8] = {hp_, hf_, he_, hp_, he_, hf_, hp_, hf_};
  const int gfx = (NP * 8 + 255) / 256;

  // ---- 2 hetero-SAGE layers: ONE gemm dispatch + ONE gf dispatch each ----
  for (int i = 0; i < 2; ++i) {
    GJobs12 js{};
    for (int r = 0; r < 8; ++r)
      js.j[r] = {hsrc[r], fw + (size_t)(i * 8 + r) * 4096, nullptr,
                 g_all + (size_t)gb[r] * 64, nsrc[r]};
    js.j[8]  = {hp_, fw + (size_t)(16 + i * 3 + 0) * 4096, nullptr, tP, NP};
    js.j[9]  = {he_, fw + (size_t)(16 + i * 3 + 1) * 4096, nullptr, tE, NE};
    js.j[10] = {hf_, fw + (size_t)(16 + i * 3 + 2) * 4096, nullptr, tF, NF};
    gemm_multi_kernel<<<dim3(gblk(NP), 11), 256, 0, stream>>>(js);

    GFPack pk;
    pk.t[0] = {g_all + (size_t)gb[0] * 64, g_all + (size_t)gb[1] * 64,
               g_all + (size_t)gb[2] * 64, tP, hp_,
               bls + (i * 3 + 0) * 64, lng + (i * 3 + 0) * 64, lnb + (i * 3 + 0) * 64,
               base[0], base[1], base[2], 3, NP};
    pk.t[1] = {g_all + (size_t)gb[3] * 64, g_all + (size_t)gb[4] * 64,
               g_all + (size_t)gb[5] * 64, tF, hf_,
               bls + (i * 3 + 2) * 64, lng + (i * 3 + 2) * 64, lnb + (i * 3 + 2) * 64,
               base[3], base[4], base[5], 3, NF};
    pk.t[2] = {g_all + (size_t)gb[6] * 64, g_all + (size_t)gb[7] * 64,
               g_all + (size_t)gb[6] * 64, tE, he_,
               bls + (i * 3 + 1) * 64, lng + (i * 3 + 1) * 64, lnb + (i * 3 + 1) * 64,
               base[6], base[7], 0, 2, NE};
    gf_kernel<<<dim3(gfx, 3), 256, 0, stream>>>(pk, srcs, off);
  }

  // ---- pool + scale ----
  float* out = (float*)d_out;
  hipMemsetAsync(out, 0, (size_t)out_size * sizeof(float), stream);
  PoolArgs pa;
  pa.h0 = hp_; pa.h1 = he_; pa.h2 = hf_;
  pa.b0 = bp; pa.b1 = be; pa.b2 = bf;
  pa.n0 = NP; pa.n1 = NE; pa.n2 = NF;
  pool_kernel<<<dim3(64 * POOL_SPLIT, 3), 256, 0, stream>>>(pa, out);
  pool_scale_kernel<<<(64 * 192 + 255) / 256, 256, 0, stream>>>(out, bp, be, bf, NP, NE, NF);
}